// Round 6
// baseline (407.787 us; speedup 1.0000x reference)
//
#include <hip/hip_runtime.h>
#include <math.h>

// Problem constants: B=2, L=2048, D=1024, H=16, hd=64, Dff=4096
#define SEQ_L 2048
#define DM    1024
#define NH    16
#define HD    64
#define BL    4096          // B*L
#define DFF   4096
#define QKV_S 3072          // fused qkv row stride

typedef __attribute__((ext_vector_type(8))) short short8;   // 8 bf16 (4 VGPRs)
typedef __attribute__((ext_vector_type(4))) short s16x4;    // 4 bf16
typedef __attribute__((ext_vector_type(4))) float f32x4;    // MFMA C/D frag

// fp32 -> bf16 round-to-nearest-even
__device__ __forceinline__ short f2bf(float x) {
    unsigned u = __float_as_uint(x);
    u += 0x7fff + ((u >> 16) & 1);
    return (short)(u >> 16);
}
__device__ __forceinline__ float bf2f(short s) {
    return __uint_as_float(((unsigned)(unsigned short)s) << 16);
}

// branch-free GELU (erf form) via A&S 7.1.26, |abs err| <= ~2e-7.
__device__ __forceinline__ float gelu_fast(float x) {
    const float xa = fabsf(x);
    const float z = xa * 0.70710678118654752440f;
    const float t = __builtin_amdgcn_rcpf(fmaf(0.3275911f, z, 1.f));
    float P = fmaf(t, 1.061405429f, -1.453152027f);
    P = fmaf(t, P, 1.421413741f);
    P = fmaf(t, P, -0.284496736f);
    P = fmaf(t, P, 0.254829592f);
    P *= t;
    const float e = __expf(-z * z);
    const float erfp = fmaf(-P, e, 1.f);   // erf(|x|/sqrt2)
    return 0.5f * fmaf(xa, erfp, x);
}

__device__ __forceinline__ float block_sum(float v, float* red, int tid) {
#pragma unroll
    for (int m = 32; m; m >>= 1) v += __shfl_xor(v, m);
    if ((tid & 63) == 0) red[tid >> 6] = v;
    __syncthreads();
    v = red[0] + red[1] + red[2] + red[3];
    __syncthreads();
    return v;
}

// ---------------------------------------------------------------------------
// Weight fp32 -> bf16: wq|wk|wv|wo|w1|w2 contiguous (fused QKV needs this).
// ---------------------------------------------------------------------------
__global__ __launch_bounds__(256) void cvt6_kernel(
    const float* __restrict__ wq, const float* __restrict__ wk,
    const float* __restrict__ wv, const float* __restrict__ wo,
    const float* __restrict__ w1, const float* __restrict__ w2,
    short* __restrict__ dst) {
    const size_t i = (size_t)blockIdx.x * 256 + threadIdx.x;  // float4 index
    const float* src;
    size_t off;
    if (i < 1048576) {
        const int seg = (int)(i >> 18);
        off = i & 262143;
        src = seg == 0 ? wq : seg == 1 ? wk : seg == 2 ? wv : wo;
    } else if (i < 2097152) { src = w1; off = i - 1048576; }
    else                    { src = w2; off = i - 2097152; }
    const float4 v = ((const float4*)src)[off];
    const s16x4 o = {f2bf(v.x), f2bf(v.y), f2bf(v.z), f2bf(v.w)};
    ((s16x4*)dst)[i] = o;
}

// ---------------------------------------------------------------------------
// LayerNorm over rows of 1024, bf16 output.
// ---------------------------------------------------------------------------
__global__ __launch_bounds__(256) void ln_bf16_kernel(const float* __restrict__ x,
                                                      const float* __restrict__ g,
                                                      const float* __restrict__ b,
                                                      short* __restrict__ out) {
    const int row = blockIdx.x;
    const int tid = threadIdx.x;
    __shared__ float red[4];
    const float4 xv = *(const float4*)(x + (size_t)row * DM + tid * 4);
    float s = xv.x + xv.y + xv.z + xv.w;
    s = block_sum(s, red, tid);
    const float mean = s * (1.f / (float)DM);
    float dx0 = xv.x - mean, dx1 = xv.y - mean, dx2 = xv.z - mean, dx3 = xv.w - mean;
    float ss = dx0 * dx0 + dx1 * dx1 + dx2 * dx2 + dx3 * dx3;
    ss = block_sum(ss, red, tid);
    const float rs = 1.f / sqrtf(ss * (1.f / (float)DM) + 1e-5f);
    const float4 gv = *(const float4*)(g + tid * 4);
    const float4 bv = *(const float4*)(b + tid * 4);
    const s16x4 ob = {f2bf(dx0 * rs * gv.x + bv.x), f2bf(dx1 * rs * gv.y + bv.y),
                      f2bf(dx2 * rs * gv.z + bv.z), f2bf(dx3 * rs * gv.w + bv.w)};
    *(s16x4*)(out + (size_t)row * DM + tid * 4) = ob;
}

// ---------------------------------------------------------------------------
// Residual + 2 partials + Poincare projection: out = project(a + c0 + c1)
// (fp32, in-place safe)
// ---------------------------------------------------------------------------
__global__ __launch_bounds__(256) void resproj3_kernel(const float* __restrict__ a,
                                                       const float* __restrict__ c0,
                                                       const float* __restrict__ c1,
                                                       float* __restrict__ out) {
    const int row = blockIdx.x;
    const int tid = threadIdx.x;
    __shared__ float red[4];
    const float4 av = *(const float4*)(a + (size_t)row * DM + tid * 4);
    const float4 c0v = *(const float4*)(c0 + (size_t)row * DM + tid * 4);
    const float4 c1v = *(const float4*)(c1 + (size_t)row * DM + tid * 4);
    float4 sv;
    sv.x = av.x + c0v.x + c1v.x;
    sv.y = av.y + c0v.y + c1v.y;
    sv.z = av.z + c0v.z + c1v.z;
    sv.w = av.w + c0v.w + c1v.w;
    float ss = sv.x * sv.x + sv.y * sv.y + sv.z * sv.z + sv.w * sv.w;
    ss = block_sum(ss, red, tid);
    const float n = sqrtf(ss);
    const float mx = 1.f - 1e-5f;
    const float scale = (n > mx) ? (mx / fmaxf(n, 1e-12f)) : 1.f;
    sv.x *= scale; sv.y *= scale; sv.z *= scale; sv.w *= scale;
    *(float4*)(out + (size_t)row * DM + tid * 4) = sv;
}

// ---------------------------------------------------------------------------
// q/k prep: per-head Poincare projection + attention-layout bf16 buffers.
// ---------------------------------------------------------------------------
__global__ __launch_bounds__(256) void qk_prep(const short* __restrict__ qkvB,
                                               short* __restrict__ Qb,
                                               short* __restrict__ Kb,
                                               float* __restrict__ k2) {
    const int tid = threadIdx.x, lane = tid & 63;
    const int vec = blockIdx.x * 4 + (tid >> 6);
    const int row = vec >> 4, h = vec & 15;
    const int b = row >> 11, l = row & 2047;
    const size_t dstv = ((size_t)(b * NH + h) * SEQ_L + l) * HD + lane;
    const float mx = 1.f - 1e-5f;
    {   // q
        const float v = bf2f(qkvB[(size_t)row * QKV_S + h * HD + lane]);
        float s = v * v;
#pragma unroll
        for (int m = 32; m; m >>= 1) s += __shfl_xor(s, m);
        const float n = sqrtf(s);
        const float sc = (n > mx) ? (mx / fmaxf(n, 1e-12f)) : 1.f;
        Qb[dstv] = f2bf(v * sc);
    }
    {   // k (+ prescaled squared norm)
        const float v = bf2f(qkvB[(size_t)row * QKV_S + DM + h * HD + lane]);
        float s = v * v;
#pragma unroll
        for (int m = 32; m; m >>= 1) s += __shfl_xor(s, m);
        const float n = sqrtf(s);
        const float sc = (n > mx) ? (mx / fmaxf(n, 1e-12f)) : 1.f;
        Kb[dstv] = f2bf(v * sc);
        if (lane == 0) k2[(size_t)(b * NH + h) * SEQ_L + l] = s * sc * sc * 0.125f;
    }
}

// ---------------------------------------------------------------------------
// v prep: transpose to Vtb [b][h][64 hd][L] bf16 via LDS tile.
// ---------------------------------------------------------------------------
__global__ __launch_bounds__(256) void v_prep(const short* __restrict__ qkvB,
                                              short* __restrict__ Vtb) {
    const int blk = blockIdx.x;
    const int bh = blk >> 5, kt = blk & 31;
    const int b = bh >> 4, h = bh & 15;
    __shared__ short T[64 * 72];
    const int tid = threadIdx.x;
    {
        const int key = tid >> 2, ch = (tid & 3) * 16;
        const size_t src = ((size_t)b * SEQ_L + kt * 64 + key) * QKV_S + 2 * DM + h * HD + ch;
        *(short8*)&T[key * 72 + ch]     = *(const short8*)(qkvB + src);
        *(short8*)&T[key * 72 + ch + 8] = *(const short8*)(qkvB + src + 8);
    }
    __syncthreads();
    const int hd = tid >> 2, kc = (tid & 3) * 16;
    short8 o0, o1;
#pragma unroll
    for (int j = 0; j < 8; ++j) {
        o0[j] = T[(kc + j) * 72 + hd];
        o1[j] = T[(kc + 8 + j) * 72 + hd];
    }
    short* dst = Vtb + ((size_t)bh * HD + hd) * SEQ_L + kt * 64 + kc;
    *(short8*)dst = o0;
    *(short8*)(dst + 8) = o1;
}

// ---------------------------------------------------------------------------
// bf16 MFMA NT GEMM, register-prefetch double buffer + optional SPLIT-K:
// grid.z in {0,1}: block handles K range [z*K, (z+1)*K) of row stride Kst;
// z==0 writes Cout (with bias), z==1 writes Cout1 (bias=0). The K-heavy
// N-narrow GEMMs (O-proj, FFN2) are latency-starved at 2 blocks/CU —
// split-K doubles resident waves (R5: MfmaUtil 20%, VALUBusy 7.6%, occ 19%).
// ---------------------------------------------------------------------------
template <int BM, int ACT, int OUTBF, int FUSED>
__global__ __launch_bounds__(256) void gemm_mfma(
    const short* __restrict__ A, const short* __restrict__ Bw,
    const float* __restrict__ bb0, const float* __restrict__ bb1,
    const float* __restrict__ bb2, void* __restrict__ Cout,
    void* __restrict__ Cout1, int M, int N, int K, int Kst) {
    constexpr int RT = BM / 32;
    constexpr bool VEPI = (OUTBF != 0) && (BM == 128);
    constexpr int SMEM_BYTES = VEPI ? (4 * 64 * 72 * 2) : ((BM * 32 + 128 * 32) * 2);
    __shared__ __align__(16) char raw[SMEM_BYTES];
    short* As = (short*)raw;
    short* Bs = As + BM * 32;
    const int tid = threadIdx.x;
    const int wv = tid >> 6, lane = tid & 63;
    const int m0 = blockIdx.y * BM, n0 = blockIdx.x * 128;
    const int zz = blockIdx.z;
    const int koff = zz * K;
    const int wr = (wv & 1) * (BM / 2);
    const int wc = (wv >> 1) * 64;

    const int arow = wv * (BM / 4) + (lane >> 2);
    const int brow = wv * 32 + (lane >> 2);
    const short* Ag = A + (size_t)(m0 + arow) * Kst + koff + (lane & 3) * 8;
    const short* Bg = Bw + (size_t)(n0 + brow) * Kst + koff + (lane & 3) * 8;
    short* AsW = As + (wv * (BM / 4)) * 32 + lane * 8;
    short* AsW2 = AsW + 16 * 32;
    short* BsW = Bs + (wv * 32) * 32 + lane * 8;
    short* BsW2 = BsW + 16 * 32;

    const f32x4 z4 = {0.f, 0.f, 0.f, 0.f};
    f32x4 acc[RT][4];
#pragma unroll
    for (int r = 0; r < RT; ++r)
#pragma unroll
        for (int c = 0; c < 4; ++c) acc[r][c] = z4;

    const int lrow = lane & 15, kq = (lane >> 4) * 8;

    // prologue: tile 0 into regs
    short8 ra0, ra1, rb0, rb1;
    ra0 = *(const short8*)(Ag);
    if constexpr (BM == 128) ra1 = *(const short8*)(Ag + (size_t)16 * Kst);
    rb0 = *(const short8*)(Bg);
    rb1 = *(const short8*)(Bg + (size_t)16 * Kst);

    for (int kt = 0; kt < K; kt += 32) {
        __syncthreads();                    // previous tile's ds_reads complete
        *(short8*)AsW = ra0;                // vmcnt wait (issued last iter) here
        if constexpr (BM == 128) *(short8*)AsW2 = ra1;
        *(short8*)BsW = rb0;
        *(short8*)BsW2 = rb1;
        short8 na0, na1, nb0, nb1;
        if (kt + 32 < K) {                  // prefetch tile k+1
            na0 = *(const short8*)(Ag + kt + 32);
            if constexpr (BM == 128) na1 = *(const short8*)(Ag + (size_t)16 * Kst + kt + 32);
            nb0 = *(const short8*)(Bg + kt + 32);
            nb1 = *(const short8*)(Bg + (size_t)16 * Kst + kt + 32);
        }
        __syncthreads();                    // LDS writes visible
        short8 af[RT], bf[4];
#pragma unroll
        for (int r = 0; r < RT; ++r)
            af[r] = *(const short8*)&As[(wr + r * 16 + lrow) * 32 + kq];
#pragma unroll
        for (int c = 0; c < 4; ++c)
            bf[c] = *(const short8*)&Bs[(wc + c * 16 + lrow) * 32 + kq];
#pragma unroll
        for (int r = 0; r < RT; ++r)
#pragma unroll
            for (int c = 0; c < 4; ++c)
                acc[r][c] = __builtin_amdgcn_mfma_f32_16x16x32_bf16(af[r], bf[c], acc[r][c], 0, 0, 0);
        ra0 = na0; ra1 = na1; rb0 = nb0; rb1 = nb1;
    }

    const int col = lane & 15, rb = (lane >> 4) * 4;
    if constexpr (VEPI) {
        __syncthreads();   // staging dead; reuse raw as per-wave transpose buffers
        short* Ot = (short*)raw + wv * (64 * 72);
#pragma unroll
        for (int c = 0; c < 4; ++c) {
            const int gn = n0 + wc + c * 16 + col;
            float bias;
            if constexpr (FUSED) {
                const int seg = gn >> 10;
                bias = (seg == 0 ? bb0 : seg == 1 ? bb1 : bb2)[gn & 1023];
            } else {
                bias = bb0[gn];
            }
#pragma unroll
            for (int r = 0; r < RT; ++r)
#pragma unroll
                for (int i = 0; i < 4; ++i) {
                    float v = acc[r][c][i] + bias;
                    if constexpr (ACT) v = gelu_fast(v);
                    Ot[(r * 16 + rb + i) * 72 + c * 16 + col] = f2bf(v);
                }
        }
        const int orow = lane >> 3, oc = (lane & 7) * 8;
#pragma unroll
        for (int it = 0; it < 8; ++it) {
            const short8 vv = *(const short8*)&Ot[(it * 8 + orow) * 72 + oc];
            *(short8*)((short*)Cout + (size_t)(m0 + wr + it * 8 + orow) * N + n0 + wc + oc) = vv;
        }
    } else {
        float* outp = (float*)(zz ? Cout1 : Cout);
#pragma unroll
        for (int c = 0; c < 4; ++c) {
            const int gn = n0 + wc + c * 16 + col;
            float bias;
            if constexpr (FUSED) {
                const int seg = gn >> 10;
                bias = (seg == 0 ? bb0 : seg == 1 ? bb1 : bb2)[gn & 1023];
            } else {
                bias = bb0[gn];
            }
            if (zz) bias = 0.f;   // split 1: partial only, bias added by split 0
#pragma unroll
            for (int r = 0; r < RT; ++r) {
                const int gm = m0 + wr + r * 16 + rb;
#pragma unroll
                for (int i = 0; i < 4; ++i) {
                    float v = acc[r][c][i] + bias;
                    if constexpr (ACT) v = gelu_fast(v);
                    if constexpr (OUTBF)
                        ((short*)outp)[(size_t)(gm + i) * N + gn] = f2bf(v);
                    else
                        outp[(size_t)(gm + i) * N + gn] = v;
                }
            }
        }
    }
}

// ---------------------------------------------------------------------------
// MFMA flash attention v2: S^T = K.Q^T, fixed max (scores bounded by the
// Poincare ball), O^T = V^T.P^T, no P round-trip.
// ---------------------------------------------------------------------------
__global__ __launch_bounds__(256) void attn_mfma2(const short* __restrict__ Qb,
                                                  const short* __restrict__ Kb,
                                                  const short* __restrict__ Vtb,
                                                  const float* __restrict__ k2v,
                                                  short* __restrict__ aO) {
    const int qt = blockIdx.x, h = blockIdx.y, b = blockIdx.z;
    const int tid = threadIdx.x, wv = tid >> 6, lane = tid & 63;
    const int bh = b * NH + h;
    __shared__ __align__(16) short smem[2 * 64 * 72];   // Ks | Vt ; reused as Ot
    short* Ks = smem;
    short* Vt = smem + 64 * 72;
    const int lrow = lane & 15, q8 = (lane >> 4) * 8, q4 = (lane >> 4) * 4;

    const short* Qh = Qb + (size_t)bh * SEQ_L * HD;
    const short* Kh = Kb + (size_t)bh * SEQ_L * HD;
    const short* Vh = Vtb + (size_t)bh * HD * SEQ_L;
    const float* k2p = k2v + (size_t)bh * SEQ_L;

    short8 qf[2][2];
#pragma unroll
    for (int nt = 0; nt < 2; ++nt)
#pragma unroll
        for (int kc = 0; kc < 2; ++kc)
            qf[nt][kc] = *(const short8*)(Qh +
                (size_t)(qt * 128 + wv * 32 + nt * 16 + lrow) * HD + kc * 32 + q8);

    const f32x4 z4 = {0.f, 0.f, 0.f, 0.f};
    f32x4 o[4][2];   // O^T accum: [ht(hd)][nt(qrow)]
#pragma unroll
    for (int ht = 0; ht < 4; ++ht)
#pragma unroll
        for (int nt = 0; nt < 2; ++nt) o[ht][nt] = z4;
    float lsum[2] = {0.f, 0.f};

    const int srow = tid >> 2, sch = (tid & 3) * 16;

    for (int kt = 0; kt < SEQ_L / 64; ++kt) {
        const int k0 = kt * 64;
        __syncthreads();
        {
            const short* g = Kh + (size_t)(k0 + srow) * HD + sch;
            *(short8*)&Ks[srow * 72 + sch]     = *(const short8*)g;
            *(short8*)&Ks[srow * 72 + sch + 8] = *(const short8*)(g + 8);
            const short* gv = Vh + (size_t)srow * SEQ_L + k0 + sch;
            *(short8*)&Vt[srow * 72 + sch]     = *(const short8*)gv;
            *(short8*)&Vt[srow * 72 + sch + 8] = *(const short8*)(gv + 8);
        }
        __syncthreads();

        short8 p8[2][2];
#pragma unroll
        for (int mt = 0; mt < 4; ++mt) {
            const short8 kf0 = *(const short8*)&Ks[(mt * 16 + lrow) * 72 + q8];
            const short8 kf1 = *(const short8*)&Ks[(mt * 16 + lrow) * 72 + 32 + q8];
            const float4 kk = *(const float4*)(k2p + k0 + mt * 16 + q4);
            const int c = mt >> 1, hi = (mt & 1) * 4;
#pragma unroll
            for (int nt = 0; nt < 2; ++nt) {
                f32x4 s = z4;
                s = __builtin_amdgcn_mfma_f32_16x16x32_bf16(kf0, qf[nt][0], s, 0, 0, 0);
                s = __builtin_amdgcn_mfma_f32_16x16x32_bf16(kf1, qf[nt][1], s, 0, 0, 0);
#pragma unroll
                for (int i = 0; i < 4; ++i) {
                    const float kki = (i == 0) ? kk.x : (i == 1) ? kk.y : (i == 2) ? kk.z : kk.w;
                    const float p = __expf(fmaf(s[i], 0.25f, -kki));
                    lsum[nt] += p;
                    p8[nt][c][hi + i] = f2bf(p);
                }
            }
        }
#pragma unroll
        for (int ht = 0; ht < 4; ++ht) {
#pragma unroll
            for (int c = 0; c < 2; ++c) {
                const s16x4 va = *(const s16x4*)&Vt[(ht * 16 + lrow) * 72 + c * 32 + q4];
                const s16x4 vb = *(const s16x4*)&Vt[(ht * 16 + lrow) * 72 + c * 32 + 16 + q4];
                const short8 v8 = {va[0], va[1], va[2], va[3], vb[0], vb[1], vb[2], vb[3]};
#pragma unroll
                for (int nt = 0; nt < 2; ++nt)
                    o[ht][nt] = __builtin_amdgcn_mfma_f32_16x16x32_bf16(v8, p8[nt][c], o[ht][nt], 0, 0, 0);
            }
        }
    }

#pragma unroll
    for (int nt = 0; nt < 2; ++nt) {
        lsum[nt] += __shfl_xor(lsum[nt], 16);
        lsum[nt] += __shfl_xor(lsum[nt], 32);
    }
    const float inv0 = 1.f / lsum[0], inv1 = 1.f / lsum[1];

    __syncthreads();
    short* Ot = smem + wv * (32 * 72);
#pragma unroll
    for (int ht = 0; ht < 4; ++ht)
#pragma unroll
        for (int nt = 0; nt < 2; ++nt) {
            const float iv = nt ? inv1 : inv0;
            const s16x4 ov = {f2bf(o[ht][nt][0] * iv), f2bf(o[ht][nt][1] * iv),
                              f2bf(o[ht][nt][2] * iv), f2bf(o[ht][nt][3] * iv)};
            *(s16x4*)&Ot[(nt * 16 + lrow) * 72 + ht * 16 + q4] = ov;
        }
    const int erow = lane >> 1, ec = (lane & 1) * 32;
    const short8 r0 = *(const short8*)&Ot[erow * 72 + ec + 0];
    const short8 r1 = *(const short8*)&Ot[erow * 72 + ec + 8];
    const short8 r2 = *(const short8*)&Ot[erow * 72 + ec + 16];
    const short8 r3 = *(const short8*)&Ot[erow * 72 + ec + 24];
    short* dst = aO + ((size_t)b * SEQ_L + qt * 128 + wv * 32 + erow) * DM + h * HD + ec;
    *(short8*)(dst + 0)  = r0;
    *(short8*)(dst + 8)  = r1;
    *(short8*)(dst + 16) = r2;
    *(short8*)(dst + 24) = r3;
}

// ---------------------------------------------------------------------------
// Launch
// ---------------------------------------------------------------------------
extern "C" void kernel_launch(void* const* d_in, const int* in_sizes, int n_in,
                              void* d_out, int out_size, void* d_ws, size_t ws_size,
                              hipStream_t stream) {
    const float* x   = (const float*)d_in[0];
    const float* wq  = (const float*)d_in[1];
    const float* bq  = (const float*)d_in[2];
    const float* wk  = (const float*)d_in[3];
    const float* bk  = (const float*)d_in[4];
    const float* wv  = (const float*)d_in[5];
    const float* bv  = (const float*)d_in[6];
    const float* wo  = (const float*)d_in[7];
    const float* bo  = (const float*)d_in[8];
    const float* g1  = (const float*)d_in[9];
    const float* b1  = (const float*)d_in[10];
    const float* g2  = (const float*)d_in[11];
    const float* b2  = (const float*)d_in[12];
    const float* w1  = (const float*)d_in[13];
    const float* bf1 = (const float*)d_in[14];
    const float* w2  = (const float*)d_in[15];
    const float* bf2 = (const float*)d_in[16];
    float* out = (float*)d_out;

    // ws layout (MiB offsets, peak ~80.25 MiB):
    // [0,24)    wbf bf16 weights: wq|wk|wv|wo [0,8), w1 [8,16), w2 [16,24)
    // [24,48)   qkvB bf16 [BL][3072]
    // [48,56)   xnb/Qb      [56,64) Kb      [64,72) Vtb/xn2b
    // [72,72.25) k2         [72.25,80.25) aO
    // O-proj partials (step 5; qkvB dead): Pa [24,41), Pb [41,58)
    // hbuf bf16 (step 8): [24,57.6)
    // FFN2 partials (step 9; wq..w1 + all attn bufs dead): Ya [0,16), Yb [58,74)
    char* base = (char*)d_ws;
    short* wbf  = (short*)base;
    short* qkvB = (short*)(base + (24u << 20));
    short* xnb  = (short*)(base + (48u << 20));
    short* Qb   = xnb;
    short* Kb   = (short*)(base + (56u << 20));
    short* Vtb  = (short*)(base + (64u << 20));
    float* k2   = (float*)(base + (72u << 20));
    short* aO   = (short*)(base + (72u << 20) + (256u << 10));
    float* Pa   = (float*)(base + (24u << 20));
    float* Pb   = (float*)(base + (41u << 20));
    short* xn2b = Vtb;
    short* hbuf = qkvB;
    float* Ya   = (float*)base;
    float* Yb   = (float*)(base + (58u << 20));

    // 0. weights -> bf16
    cvt6_kernel<<<12288, 256, 0, stream>>>(wq, wk, wv, wo, w1, w2, wbf);
    // 1. LN1 -> bf16
    ln_bf16_kernel<<<BL, 256, 0, stream>>>(x, g1, b1, xnb);
    // 2. fused QKV projection -> bf16 [BL][3072]
    gemm_mfma<128, 0, 1, 1><<<dim3(24, 32), 256, 0, stream>>>(
        xnb, wbf, bq, bk, bv, qkvB, nullptr, BL, QKV_S, DM, DM);
    // 3. prep: project q,k -> Qb/Kb [bh][L][64] + k2; transpose v -> Vtb
    qk_prep<<<16384, 256, 0, stream>>>(qkvB, Qb, Kb, k2);
    v_prep<<<1024, 256, 0, stream>>>(qkvB, Vtb);
    // 4. flash MFMA attention -> aO bf16
    attn_mfma2<<<dim3(16, 16, 2), 256, 0, stream>>>(Qb, Kb, Vtb, k2, aO);
    // 5. output projection, split-K=2 -> partials Pa, Pb
    gemm_mfma<64, 0, 0, 0><<<dim3(8, 64, 2), 256, 0, stream>>>(
        aO, wbf + 3145728, bo, bo, bo, Pa, Pb, BL, DM, DM / 2, DM);
    // 6. x1 = project(x + Pa + Pb) -> d_out
    resproj3_kernel<<<BL, 256, 0, stream>>>(x, Pa, Pb, out);
    // 7. LN2 -> bf16
    ln_bf16_kernel<<<BL, 256, 0, stream>>>(out, g2, b2, xn2b);
    // 8. FFN1 + GELU -> bf16 hidden
    gemm_mfma<128, 1, 1, 0><<<dim3(32, 32), 256, 0, stream>>>(
        xn2b, wbf + 4194304, bf1, bf1, bf1, hbuf, nullptr, BL, DFF, DM, DM);
    // 9. FFN2, split-K=2 -> partials Ya, Yb
    gemm_mfma<64, 0, 0, 0><<<dim3(8, 64, 2), 256, 0, stream>>>(
        hbuf, wbf + 8388608, bf2, bf2, bf2, Ya, Yb, BL, DM, DFF / 2, DFF);
    // 10. out = project(x1 + Ya + Yb)
    resproj3_kernel<<<BL, 256, 0, stream>>>(out, Ya, Yb, out);
}